// Round 2
// baseline (398.099 us; speedup 1.0000x reference)
//
#include <hip/hip_runtime.h>
#include <math.h>

#define MESH 4194304
#define NBLOCKS 2048
#define NTHREADS 256
#define KPT 8  // elements per thread; 2048*256*8 == MESH

// rotate v by angle t; t==0 gives identity (used for element 0)
__device__ __forceinline__ float2 rot2(float t, float2 v) {
  float s, c;
  __sincosf(t, &s, &c);
  return make_float2(c * v.x - s * v.y, s * v.x + c * v.y);
}

__global__ void init_ws_kernel(double* __restrict__ acc, unsigned* __restrict__ counter) {
  if (threadIdx.x < 4) acc[threadIdx.x] = 0.0;
  if (threadIdx.x == 0) *counter = 0u;
}

// Single fused kernel: phase1 (vols sums) -> grid barrier -> phase2 (loss_so2).
// Co-residency: 2048 blocks * 4 waves = 8192 waves = 256 CU * 32 waves.
// __launch_bounds__(256,8) forces <=64 VGPR; LDS 16.4 KB <= 160/8 KB.
__global__ __launch_bounds__(NTHREADS, 8)
void fused_kernel(const float* __restrict__ theta,
                  const float2* __restrict__ state,
                  double* __restrict__ acc,
                  unsigned* __restrict__ counter) {
  __shared__ float lds_v[KPT * NTHREADS];  // exp-arg per element
  __shared__ float lds_w[KPT * NTHREADS];  // weight per element
  __shared__ float red1[4], red2[4];
  __shared__ float bcast_avg;

  const int tid = threadIdx.x;
  const int lane = tid & 63;
  const int wid = tid >> 6;
  // each wave owns 512 contiguous elements; lane-coalesced within each k-slab
  const int base = ((blockIdx.x * 4 + wid) << 9) + lane;

  // ---- preload: 16 independent loads in flight ----
  float th[KPT];   // theta_eff[e] = (e==0) ? 0 : theta[e-1]
  float2 st[KPT];
  #pragma unroll
  for (int k = 0; k < KPT; ++k) {
    const int e = base + (k << 6);
    st[k] = state[e];
    th[k] = (e == 0) ? 0.f : theta[e - 1];
  }
  // boundary (lane 63 at k==7 needs element e+1 owned by the next wave)
  float thx = 0.f;                      // theta_eff[e_last+1]; 0 at global wrap
  float2 stx = make_float2(0.f, 0.f);
  if (lane == 63) {
    const int en = base + 448 + 1;      // e_last + 1
    if (en == MESH) {
      stx = state[0];                   // deformed[0] = state[0]
    } else {
      thx = theta[en - 1];
      stx = state[en];
    }
  }
  const bool glast = (base + 448 == MESH - 1);  // this lane owns element M-1

  // ---- phase 1: vols, loss_v, loss_s; stash exp-args & weights in LDS ----
  float lv = 0.f, ls = 0.f;
  float2 dnext = rot2(th[0], st[0]);
  const float2 dbnd = rot2(thx, stx);
  #pragma unroll
  for (int k = 0; k < KPT; ++k) {
    const float2 dcur = dnext;
    float dnx = __shfl_down(dcur.x, 1);
    float dny = __shfl_down(dcur.y, 1);
    float thn = __shfl_down(th[k], 1);
    if (k < KPT - 1) {
      dnext = rot2(th[k + 1], st[k + 1]);
      const float bx = __shfl(dnext.x, 0);
      const float by = __shfl(dnext.y, 0);
      const float tb = __shfl(th[k + 1], 0);
      if (lane == 63) { dnx = bx; dny = by; thn = tb; }
    } else {
      if (lane == 63) { dnx = dbnd.x; dny = dbnd.y; thn = thx; }
    }
    const float dot = dcur.x * dnx + dcur.y * dny;
    const float v2s = 1.f - dot * dot;  // signed, for sim_last
    const float v2 = fabsf(v2s);
    const float vol = sqrtf(v2);
    lv += vol;
    ls += v2;
    // weight: e==0 -> |0-theta[0]|; 1..M-2 -> |theta[e-1]-theta[e]|;
    // e==M-1 -> thn==0 -> |theta[M-2]|  (all uniform via theta_eff)
    const float w = fabsf(th[k] - thn);
    const float earg = (glast && k == KPT - 1) ? v2s : vol;  // sim_last: no sqrt/abs
    lds_v[(k << 8) + tid] = earg;
    lds_w[(k << 8) + tid] = w;
  }

  #pragma unroll
  for (int off = 32; off > 0; off >>= 1) {
    lv += __shfl_down(lv, off);
    ls += __shfl_down(ls, off);
  }
  if (lane == 0) { red1[wid] = lv; red2[wid] = ls; }
  __syncthreads();

  // ---- grid barrier (device-scope acq/rel counter, all blocks co-resident) ----
  if (tid == 0) {
    atomicAdd(&acc[0], (double)(red1[0] + red1[1] + red1[2] + red1[3]));
    atomicAdd(&acc[1], (double)(red2[0] + red2[1] + red2[2] + red2[3]));
    __hip_atomic_fetch_add(counter, 1u, __ATOMIC_ACQ_REL, __HIP_MEMORY_SCOPE_AGENT);
    while (__hip_atomic_load(counter, __ATOMIC_ACQUIRE, __HIP_MEMORY_SCOPE_AGENT) < NBLOCKS) {
      __builtin_amdgcn_s_sleep(2);
    }
    const double a0 = __hip_atomic_load(&acc[0], __ATOMIC_RELAXED, __HIP_MEMORY_SCOPE_AGENT);
    bcast_avg = (float)(fabs(a0) / (double)MESH);
  }
  __syncthreads();

  // ---- phase 2: loss_so2 from LDS ----
  const float inv_avg = 1.0f / bcast_avg;
  float lso = 0.f;
  #pragma unroll
  for (int k = 0; k < KPT; ++k) {
    lso += lds_w[(k << 8) + tid] * __expf(-lds_v[(k << 8) + tid] * inv_avg);
  }
  #pragma unroll
  for (int off = 32; off > 0; off >>= 1) lso += __shfl_down(lso, off);
  if (lane == 0) red1[wid] = lso;
  __syncthreads();
  if (tid == 0) atomicAdd(&acc[2], (double)(red1[0] + red1[1] + red1[2] + red1[3]));
}

__global__ void finalize_kernel(const double* __restrict__ acc, float* __restrict__ out) {
  out[0] = (float)(acc[0] + acc[1] + acc[2]);
}

extern "C" void kernel_launch(void* const* d_in, const int* in_sizes, int n_in,
                              void* d_out, int out_size, void* d_ws, size_t ws_size,
                              hipStream_t stream) {
  const float* theta = (const float*)d_in[0];    // (MESH-1,) f32
  const float2* state = (const float2*)d_in[1];  // (MESH, 2) f32
  double* acc = (double*)d_ws;                   // acc[0..3]
  unsigned* counter = (unsigned*)(acc + 4);      // barrier counter
  float* out = (float*)d_out;

  init_ws_kernel<<<1, 64, 0, stream>>>(acc, counter);
  fused_kernel<<<NBLOCKS, NTHREADS, 0, stream>>>(theta, state, acc, counter);
  finalize_kernel<<<1, 1, 0, stream>>>(acc, out);
}

// Round 3
// 102.285 us; speedup vs baseline: 3.8920x; 3.8920x over previous
//
#include <hip/hip_runtime.h>
#include <math.h>

#define MESH 4194304
#define NBLOCKS 2048
#define NTHREADS 256
#define KPT 8  // 2048*256*8 == MESH
#define STRIDE (NBLOCKS * NTHREADS)

// rotate v by angle t; t==0 gives identity (element 0 / wraparound)
__device__ __forceinline__ float2 rot2(float t, float2 v) {
  float s, c;
  __sincosf(t, &s, &c);
  return make_float2(c * v.x - s * v.y, s * v.x + c * v.y);
}

__device__ __forceinline__ float block_reduce(float v, float* red) {
  #pragma unroll
  for (int off = 32; off > 0; off >>= 1) v += __shfl_down(v, off);
  const int lane = threadIdx.x & 63, wid = threadIdx.x >> 6;
  if (lane == 0) red[wid] = v;
  __syncthreads();
  return red[0] + red[1] + red[2] + red[3];
}

// Pass A: per-block partial sums of vols and vols^2 -> pv[block] (plain store)
__global__ void passA_kernel(const float* __restrict__ theta,
                             const float2* __restrict__ state,
                             float2* __restrict__ pv) {
  const int tid0 = blockIdx.x * NTHREADS + threadIdx.x;
  float th_a[KPT], th_b[KPT];
  float2 st_a[KPT], st_b[KPT];
  #pragma unroll
  for (int k = 0; k < KPT; ++k) {  // all loads independent & hoisted: max MLP
    const int i = tid0 + k * STRIDE;
    const int ip1 = (i + 1 == MESH) ? 0 : i + 1;
    th_a[k] = (i == 0) ? 0.f : theta[i - 1];
    th_b[k] = (ip1 == 0) ? 0.f : theta[ip1 - 1];
    st_a[k] = state[i];
    st_b[k] = state[ip1];
  }
  float lv = 0.f, ls = 0.f;
  #pragma unroll
  for (int k = 0; k < KPT; ++k) {
    const float2 a = rot2(th_a[k], st_a[k]);
    const float2 b = rot2(th_b[k], st_b[k]);
    const float dot = a.x * b.x + a.y * b.y;
    const float v2 = fabsf(1.f - dot * dot);
    lv += sqrtf(v2);
    ls += v2;
  }
  __shared__ float red1[4], red2[4];
  const float blv = block_reduce(lv, red1);
  const float bls = block_reduce(ls, red2);
  if (threadIdx.x == 0) pv[blockIdx.x] = make_float2(blv, bls);
}

// Reduce A partials: acc[0] = loss_v + loss_s; inv_avg = M / |loss_v|
__global__ void reduceA_kernel(const float2* __restrict__ pv,
                               double* __restrict__ acc,
                               float* __restrict__ inv_avg) {
  double lv = 0.0, ls = 0.0;
  for (int i = threadIdx.x; i < NBLOCKS; i += 1024) {
    const float2 p = pv[i];
    lv += (double)p.x;
    ls += (double)p.y;
  }
  #pragma unroll
  for (int off = 32; off > 0; off >>= 1) {
    lv += __shfl_down(lv, off);
    ls += __shfl_down(ls, off);
  }
  __shared__ double s1[16], s2[16];
  const int lane = threadIdx.x & 63, wid = threadIdx.x >> 6;
  if (lane == 0) { s1[wid] = lv; s2[wid] = ls; }
  __syncthreads();
  if (threadIdx.x == 0) {
    double tlv = 0.0, tls = 0.0;
    #pragma unroll
    for (int w = 0; w < 16; ++w) { tlv += s1[w]; tls += s2[w]; }
    acc[0] = tlv + tls;
    *inv_avg = (float)((double)MESH / fabs(tlv));
  }
}

// Pass C: per-block partial of loss_so2 -> pl[block]
__global__ void passC_kernel(const float* __restrict__ theta,
                             const float2* __restrict__ state,
                             const float* __restrict__ inv_avg_p,
                             float* __restrict__ pl) {
  const float inv_avg = *inv_avg_p;  // uniform scalar load, L2-hot
  const int tid0 = blockIdx.x * NTHREADS + threadIdx.x;
  float th_a[KPT], th_b[KPT];
  float2 st_a[KPT], st_b[KPT];
  #pragma unroll
  for (int k = 0; k < KPT; ++k) {
    const int i = tid0 + k * STRIDE;
    const int ip1 = (i + 1 == MESH) ? 0 : i + 1;
    th_a[k] = (i == 0) ? 0.f : theta[i - 1];
    th_b[k] = (ip1 == 0) ? 0.f : theta[ip1 - 1];
    st_a[k] = state[i];
    st_b[k] = state[ip1];
  }
  float lso = 0.f;
  #pragma unroll
  for (int k = 0; k < KPT; ++k) {
    const int i = tid0 + k * STRIDE;
    const float2 a = rot2(th_a[k], st_a[k]);
    const float2 b = rot2(th_b[k], st_b[k]);
    const float dot = a.x * b.x + a.y * b.y;
    const float v2s = 1.f - dot * dot;
    // weight: uniform |theta_eff[i] - theta_eff[i+1]| covers j=0 (|theta[0]|),
    // interior (|theta[j-1]-theta[j]|), and j=M-1 (|theta[M-2]|, th_b==0)
    const float w = fabsf(th_a[k] - th_b[k]);
    // exp-arg: vols[j] everywhere except j==M-1: signed 1-dot^2, no sqrt/abs
    const float earg = (i == MESH - 1) ? v2s : sqrtf(fabsf(v2s));
    lso += w * __expf(-earg * inv_avg);
  }
  __shared__ float red1[4];
  const float blso = block_reduce(lso, red1);
  if (threadIdx.x == 0) pl[blockIdx.x] = blso;
}

// Reduce C partials + finalize
__global__ void reduceC_kernel(const float* __restrict__ pl,
                               const double* __restrict__ acc,
                               float* __restrict__ out) {
  double lso = 0.0;
  for (int i = threadIdx.x; i < NBLOCKS; i += 1024) lso += (double)pl[i];
  #pragma unroll
  for (int off = 32; off > 0; off >>= 1) lso += __shfl_down(lso, off);
  __shared__ double s1[16];
  const int lane = threadIdx.x & 63, wid = threadIdx.x >> 6;
  if (lane == 0) s1[wid] = lso;
  __syncthreads();
  if (threadIdx.x == 0) {
    double t = 0.0;
    #pragma unroll
    for (int w = 0; w < 16; ++w) t += s1[w];
    out[0] = (float)(acc[0] + t);
  }
}

extern "C" void kernel_launch(void* const* d_in, const int* in_sizes, int n_in,
                              void* d_out, int out_size, void* d_ws, size_t ws_size,
                              hipStream_t stream) {
  const float* theta  = (const float*)d_in[0];   // (MESH-1,) f32
  const float2* state = (const float2*)d_in[1];  // (MESH, 2) f32
  float* out = (float*)d_out;

  // ws layout: pv float2[2048] @0 (16KB) | pl float[2048] @16K (8KB)
  //            acc double[2] @24K | inv_avg float @24K+16
  char* ws = (char*)d_ws;
  float2* pv = (float2*)ws;
  float* pl = (float*)(ws + 16384);
  double* acc = (double*)(ws + 24576);
  float* inv_avg = (float*)(ws + 24576 + 16);

  passA_kernel<<<NBLOCKS, NTHREADS, 0, stream>>>(theta, state, pv);
  reduceA_kernel<<<1, 1024, 0, stream>>>(pv, acc, inv_avg);
  passC_kernel<<<NBLOCKS, NTHREADS, 0, stream>>>(theta, state, inv_avg, pl);
  reduceC_kernel<<<1, 1024, 0, stream>>>(pl, acc, out);
}

// Round 4
// 98.003 us; speedup vs baseline: 4.0621x; 1.0437x over previous
//
#include <hip/hip_runtime.h>
#include <math.h>

#define MESH 4194304
#define NBLOCKS 2048
#define NTHREADS 256
#define QPG 2  // quad-groups per thread; 2048 blocks * 4 waves * 2 groups * 64 lanes * 4 elem == MESH

__device__ __forceinline__ float2 rot2(float t, float x, float y) {
  float s, c;
  __sincosf(t, &s, &c);
  return make_float2(c * x - s * y, s * x + c * y);
}

__device__ __forceinline__ float block_reduce(float v, float* red) {
  #pragma unroll
  for (int off = 32; off > 0; off >>= 1) v += __shfl_down(v, off);
  const int lane = threadIdx.x & 63, wid = threadIdx.x >> 6;
  if (lane == 0) red[wid] = v;
  __syncthreads();
  return red[0] + red[1] + red[2] + red[3];
}

// One pass kernel, templated: PASS_C=false -> (sum vols, sum vols^2);
// PASS_C=true -> sum w*exp(-earg/avg).
// Layout: wave owns 512 contiguous elements; group g: lane owns quad
// e0 = wbase + g*256 + lane*4. Loads: 1 float4 theta + 2 float4 state per quad
// (aligned, fully coalesced). Neighbor data via shuffles + per-wave carries.
template <bool PASS_C>
__global__ void pass_kernel(const float* __restrict__ theta,
                            const float* __restrict__ statef,
                            const float* __restrict__ inv_avg_p,
                            float2* __restrict__ pv,
                            float* __restrict__ pl) {
  const int tid = threadIdx.x;
  const int lane = tid & 63, wid = tid >> 6;
  const int wbase = (blockIdx.x * 4 + wid) << 9;  // wave's first element

  // ---- hoisted loads: 6 vector loads + 2 predicated scalars, all in flight ----
  float4 tf[QPG], sA[QPG], sB[QPG];
  #pragma unroll
  for (int g = 0; g < QPG; ++g) {
    const int e0 = wbase + (g << 8) + (lane << 2);
    if (e0 != MESH - 4) {
      tf[g] = *(const float4*)(theta + e0);          // theta_eff[e0+1..e0+4]
    } else {                                          // avoid 4B overread; wrap angle = 0
      tf[g] = make_float4(theta[e0], theta[e0 + 1], theta[e0 + 2], 0.f);
    }
    sA[g] = *(const float4*)(statef + 2 * e0);       // state[e0], state[e0+1]
    sB[g] = *(const float4*)(statef + 2 * e0 + 4);   // state[e0+2], state[e0+3]
  }
  float th_carry = 0.f;  // theta_eff[wbase] for lane 0 of g==0
  if (lane == 0 && wbase > 0) th_carry = theta[wbase - 1];
  float2 s_carry = make_float2(0.f, 0.f);  // state[wbase+512] for lane 63 of last group
  if (lane == 63) {
    const int en = (wbase + 512 == MESH) ? 0 : wbase + 512;
    s_carry = make_float2(statef[2 * en], statef[2 * en + 1]);
  }
  const float inv_avg = PASS_C ? *inv_avg_p : 0.f;

  float acc0 = 0.f, acc1 = 0.f;
  #pragma unroll
  for (int g = 0; g < QPG; ++g) {
    const int e0 = wbase + (g << 8) + (lane << 2);
    // theta_eff[e0]: previous quad's tf.w
    const float prevw = (g == 0) ? th_carry : __shfl(tf[g - 1].w, 63);
    float th0 = __shfl_up(tf[g].w, 1);
    if (lane == 0) th0 = prevw;
    // state[e0+4]: next quad's first state
    const float bx = (g + 1 < QPG) ? __shfl(sA[g + 1].x, 0) : s_carry.x;
    const float by = (g + 1 < QPG) ? __shfl(sA[g + 1].y, 0) : s_carry.y;
    float nx = __shfl_down(sA[g].x, 1);
    float ny = __shfl_down(sA[g].y, 1);
    if (lane == 63) { nx = bx; ny = by; }

    // each deformed computed exactly once
    const float2 d0 = rot2(th0,     sA[g].x, sA[g].y);
    const float2 d1 = rot2(tf[g].x, sA[g].z, sA[g].w);
    const float2 d2 = rot2(tf[g].y, sB[g].x, sB[g].y);
    const float2 d3 = rot2(tf[g].z, sB[g].z, sB[g].w);
    const float2 d4 = rot2(tf[g].w, nx, ny);

    const float dots[4] = {d0.x * d1.x + d0.y * d1.y, d1.x * d2.x + d1.y * d2.y,
                           d2.x * d3.x + d2.y * d3.y, d3.x * d4.x + d3.y * d4.y};
    if (!PASS_C) {
      #pragma unroll
      for (int j = 0; j < 4; ++j) {
        const float v2 = fabsf(1.f - dots[j] * dots[j]);
        acc0 += sqrtf(v2);
        acc1 += v2;
      }
    } else {
      const float thseq[5] = {th0, tf[g].x, tf[g].y, tf[g].z, tf[g].w};
      #pragma unroll
      for (int j = 0; j < 4; ++j) {
        const float v2s = 1.f - dots[j] * dots[j];
        // w[e]=|theta_eff[e]-theta_eff[e+1]| covers j=0 (|th0|), interior, and
        // e==M-1 (tf.w==0 -> |theta[M-2]|) uniformly
        const float w = fabsf(thseq[j] - thseq[j + 1]);
        // exp-arg: vols everywhere except e==M-1 (signed 1-dot^2, no sqrt/abs)
        const float earg = (e0 == MESH - 4 && j == 3) ? v2s : sqrtf(fabsf(v2s));
        acc0 += w * __expf(-earg * inv_avg);
      }
    }
  }

  __shared__ float red1[4], red2[4];
  if (!PASS_C) {
    const float b0 = block_reduce(acc0, red1);
    const float b1 = block_reduce(acc1, red2);
    if (tid == 0) pv[blockIdx.x] = make_float2(b0, b1);
  } else {
    const float b0 = block_reduce(acc0, red1);
    if (tid == 0) pl[blockIdx.x] = b0;
  }
}

// Reduce A partials: acc[0] = loss_v + loss_s; inv_avg = M / |loss_v|
__global__ void reduceA_kernel(const float2* __restrict__ pv,
                               double* __restrict__ acc,
                               float* __restrict__ inv_avg) {
  double lv = 0.0, ls = 0.0;
  for (int i = threadIdx.x; i < NBLOCKS; i += 1024) {
    const float2 p = pv[i];
    lv += (double)p.x;
    ls += (double)p.y;
  }
  #pragma unroll
  for (int off = 32; off > 0; off >>= 1) {
    lv += __shfl_down(lv, off);
    ls += __shfl_down(ls, off);
  }
  __shared__ double s1[16], s2[16];
  const int lane = threadIdx.x & 63, wid = threadIdx.x >> 6;
  if (lane == 0) { s1[wid] = lv; s2[wid] = ls; }
  __syncthreads();
  if (threadIdx.x == 0) {
    double tlv = 0.0, tls = 0.0;
    #pragma unroll
    for (int w = 0; w < 16; ++w) { tlv += s1[w]; tls += s2[w]; }
    acc[0] = tlv + tls;
    *inv_avg = (float)((double)MESH / fabs(tlv));
  }
}

// Reduce C partials + finalize
__global__ void reduceC_kernel(const float* __restrict__ pl,
                               const double* __restrict__ acc,
                               float* __restrict__ out) {
  double lso = 0.0;
  for (int i = threadIdx.x; i < NBLOCKS; i += 1024) lso += (double)pl[i];
  #pragma unroll
  for (int off = 32; off > 0; off >>= 1) lso += __shfl_down(lso, off);
  __shared__ double s1[16];
  const int lane = threadIdx.x & 63, wid = threadIdx.x >> 6;
  if (lane == 0) s1[wid] = lso;
  __syncthreads();
  if (threadIdx.x == 0) {
    double t = 0.0;
    #pragma unroll
    for (int w = 0; w < 16; ++w) t += s1[w];
    out[0] = (float)(acc[0] + t);
  }
}

extern "C" void kernel_launch(void* const* d_in, const int* in_sizes, int n_in,
                              void* d_out, int out_size, void* d_ws, size_t ws_size,
                              hipStream_t stream) {
  const float* theta  = (const float*)d_in[0];   // (MESH-1,) f32
  const float* statef = (const float*)d_in[1];   // (MESH, 2) f32 flat
  float* out = (float*)d_out;

  // ws layout: pv float2[2048] @0 | pl float[2048] @16K | acc double[2] @24K | inv_avg @24K+16
  char* ws = (char*)d_ws;
  float2* pv = (float2*)ws;
  float* pl = (float*)(ws + 16384);
  double* acc = (double*)(ws + 24576);
  float* inv_avg = (float*)(ws + 24576 + 16);

  pass_kernel<false><<<NBLOCKS, NTHREADS, 0, stream>>>(theta, statef, inv_avg, pv, pl);
  reduceA_kernel<<<1, 1024, 0, stream>>>(pv, acc, inv_avg);
  pass_kernel<true><<<NBLOCKS, NTHREADS, 0, stream>>>(theta, statef, inv_avg, pv, pl);
  reduceC_kernel<<<1, 1024, 0, stream>>>(pl, acc, out);
}